// Round 15
// baseline (62.569 us; speedup 1.0000x reference)
//
#include <hip/hip_runtime.h>

#define CCH 128
#define SP  4096          // 64*64 spatial positions per (b,c)
#define BROWS 10          // band rows rb in [0,10)
#define RSTR 68           // g rb-stride (floats): banks 4*rb -> conflict-free b128
#define BSZ2 (BROWS * RSTR)  // 680 floats per band
#define GOFF 16           // g data starts at 16 (64B-aligned); g[0] = sentinel 0
#define GTOT (GOFF + 9 * BSZ2)   // 6136 floats = 24.5 KB
#define T16_OFF 65536     // byte offset of the u16 (s=8) table in d_ws
#define SCR_OFFB 131072   // byte offset of attnmax diagnostic scratch in d_ws
#define TBLK 80           // table-generator blocks fused into conv grid
#define XTSTR 136         // LDS x_t halfword stride (272B rows)
#define REPS 4            // DIAGNOSTIC amplification (see round-15 notes)

typedef __attribute__((ext_vector_type(8))) short bf16x8;   // 8 bf16 = 4 VGPRs
typedef __attribute__((ext_vector_type(4))) float f32x4;

__device__ __forceinline__ float sigmoidf_(float z) {
  return 1.0f / (1.0f + __expf(-z));
}

__device__ __forceinline__ unsigned short bf16rne(float f) {
  union { float f; unsigned u; } v; v.f = f;
  return (unsigned short)((v.u + 0x7fffu + ((v.u >> 16) & 1u)) >> 16);
}

// Band-local gather offset for tap s at output wh (g layout [s][rb][sh]):
// GOFF + s*680 + rb*68 + sh, or 0 (sentinel g[0]=0) when source is OOB.
__device__ __forceinline__ int tap_off(int s, int wh) {
  int q  = (s << 12) + wh;     // flat index into torch's reinterpreted view
  int wi = q / 576;  int r  = q - wi * 576;
  int hi = r / 9;    int kk = r - hi * 9;
  int di = kk / 3,   dj = kk - di * 3;
  int sw = wi + di - 1, sh = hi + dj - 1;
  bool valid = ((unsigned)sw < 64u) & ((unsigned)sh < 64u);
  int wilo = (s * 64) / 9;     // first source row of band s
  int rb = sw - wilo + 1;      // in [0,10) for valid sw
  return valid ? (GOFF + s * BSZ2 + rb * RSTR + sh) : 0;
}

// Fused: blocks [0,TBLK) generate gather tables; blocks [TBLK,..) do the conv.
// DIAGNOSTIC: conv body repeated REPS x (idempotent: same y written each rep)
// so the dispatch rises above the harness fill kernels in the profile top-5.
template <bool WS>
__global__ __launch_bounds__(256) void k_conv(
    const float* __restrict__ x, const float* __restrict__ attn_w,
    float* __restrict__ y, unsigned* __restrict__ t32,
    unsigned short* __restrict__ t16) {
  int bid = blockIdx.x;
  if (WS) {
    if (bid < TBLK) {   // table generation: 20480 entries, one per thread
      int i = bid * 256 + threadIdx.x;
      if (i < 4 * SP) {
        int wh = i >> 2, j = i & 3;         // t32[wh*4+j] -> taps 2j, 2j+1
        unsigned lo = (unsigned)tap_off(2 * j, wh);
        unsigned hi = (unsigned)tap_off(2 * j + 1, wh);
        t32[i] = lo | (hi << 16);
      } else if (i < 5 * SP) {
        int wh = i & (SP - 1);
        t16[wh] = (unsigned short)tap_off(8, wh);
      }
      return;
    }
    bid -= TBLK;
  }

  __shared__ unsigned short x_t[32 * XTSTR];   // 8704 B

  int b  = bid >> 7;
  int nb = bid & 127;                          // 32n slab
  int lane = threadIdx.x & 63, wv = threadIdx.x >> 6;

  // A-fragments from fp32 w (L2-hot 64KB): lane l holds
  // A[o = ot*16 + (l&15)][k = ks*32 + (l>>4)*8 .. +7], converted to bf16.
  bf16x8 afrag[2][4];
#pragma unroll
  for (int ot = 0; ot < 2; ot++)
#pragma unroll
    for (int ks = 0; ks < 4; ks++) {
      int o = (wv << 5) + (ot << 4) + (lane & 15);
      int k = (ks << 5) + ((lane >> 4) << 3);
      const float4* wp = (const float4*)&attn_w[(o << 7) + k];
      float4 a0 = wp[0], a1 = wp[1];
      bf16x8 f;
      f[0] = (short)bf16rne(a0.x); f[1] = (short)bf16rne(a0.y);
      f[2] = (short)bf16rne(a0.z); f[3] = (short)bf16rne(a0.w);
      f[4] = (short)bf16rne(a1.x); f[5] = (short)bf16rne(a1.y);
      f[6] = (short)bf16rne(a1.z); f[7] = (short)bf16rne(a1.w);
      afrag[ot][ks] = f;
    }

  const float* xpb = x + ((size_t)b << 19) + (nb << 5);
  int n_st  = threadIdx.x & 31;
  int c_st  = (threadIdx.x >> 5) << 2;

  int reps = WS ? REPS : 1;
  for (int rep = 0; rep < reps; rep++) {
    // Staging loads (16 scalar dwords; lanes 0-31 = 128B segments).
    float xv[16];
#pragma unroll
    for (int g = 0; g < 4; g++) {
      int c0 = c_st + (g << 5);
#pragma unroll
      for (int i = 0; i < 4; i++)
        xv[g * 4 + i] = xpb[((size_t)(c0 + i) << 12) + n_st];
    }
    // Convert + write staged x into transposed bf16 LDS x_t[n][k].
#pragma unroll
    for (int g = 0; g < 4; g++) {
      int c0 = c_st + (g << 5);
      union { unsigned short s[2]; unsigned u; } p0, p1;
      p0.s[0] = bf16rne(xv[g * 4 + 0]); p0.s[1] = bf16rne(xv[g * 4 + 1]);
      p1.s[0] = bf16rne(xv[g * 4 + 2]); p1.s[1] = bf16rne(xv[g * 4 + 3]);
      *(uint2*)&x_t[n_st * XTSTR + c0] = make_uint2(p0.u, p1.u);
    }
    __syncthreads();

    f32x4 acc[2][2] = {};
#pragma unroll
    for (int ks = 0; ks < 4; ks++) {
      bf16x8 bfrag[2];
#pragma unroll
      for (int nt = 0; nt < 2; nt++) {
        int n = (nt << 4) + (lane & 15);
        int k = (ks << 5) + ((lane >> 4) << 3);
        bfrag[nt] = *(const bf16x8*)&x_t[n * XTSTR + k];   // ds_read_b128
      }
#pragma unroll
      for (int ot = 0; ot < 2; ot++)
#pragma unroll
        for (int nt = 0; nt < 2; nt++)
          acc[ot][nt] = __builtin_amdgcn_mfma_f32_16x16x32_bf16(
              afrag[ot][ks], bfrag[nt], acc[ot][nt], 0, 0, 0);
    }

    // Epilogue: acc[ot][nt][r] -> y[o][n], o = base + (lane>>4)*4 + r.
    float* yb = y + ((size_t)b << 19) + (nb << 5);
#pragma unroll
    for (int ot = 0; ot < 2; ot++) {
      int ob = (wv << 5) + (ot << 4) + ((lane >> 4) << 2);
#pragma unroll
      for (int nt = 0; nt < 2; nt++) {
        int n = (nt << 4) + (lane & 15);
#pragma unroll
        for (int r = 0; r < 4; r++)
          yb[((size_t)(ob + r) << 12) + n] = acc[ot][nt][r];
      }
    }
    __syncthreads();   // LDS reuse guard for next rep
  }
}

// out[b,c,wh] = max_s G_s[src(s,wh)].  DIAGNOSTIC: body repeated REPS x;
// reps 0..REPS-2 write to private scratch (deterministic, never read),
// final rep writes the real output over the y-plane.
template <bool TBL>
__global__ __launch_bounds__(256) void k_attnmax(
    const float* __restrict__ x, float* __restrict__ yo,
    const float* __restrict__ se_param, const float* __restrict__ attn_b,
    const uint4* __restrict__ t32, const unsigned short* __restrict__ t16,
    float* __restrict__ scratch) {
  __shared__ float g[GTOT];
  __shared__ float se9[16];

  int bc = blockIdx.x;            // b*128 + c
  int c  = bc & (CCH - 1);
  const float* xp = x  + ((size_t)bc << 12);
  float*       yp = yo + ((size_t)bc << 12);

  if (threadIdx.x < 9) se9[threadIdx.x] = sigmoidf_(se_param[threadIdx.x]);
  if (threadIdx.x == 0) g[0] = 0.0f;
  float ab = attn_b[c];
  __syncthreads();

  int reps = TBL ? REPS : 1;
  for (int rep = 0; rep < reps; rep++) {
    // Phase 1: 1440 float4 units -> (s, rb, sh0). Source row rg = wilo(s)-1+rb.
    for (int f = threadIdx.x; f < 9 * BROWS * 16; f += 256) {
      int s   = f / 160;
      int rem = f - s * 160;
      int rb  = rem >> 4, sh0 = (rem & 15) << 2;
      int rg  = ((s * 64 * 58255) >> 19) - 1 + rb;   // wilo(s) = (s*64)/9
      float4 gv = make_float4(0.0f, 0.0f, 0.0f, 0.0f);
      if ((unsigned)rg < 64u) {
        float se = se9[s];
        float4 xx = *(const float4*)&xp[(rg << 6) + sh0];   // 1KB/wave coalesced
        float4 yy = *(const float4*)&yp[(rg << 6) + sh0];
        gv.x = se * xx.x * sigmoidf_(fmaf(se, yy.x, ab));
        gv.y = se * xx.y * sigmoidf_(fmaf(se, yy.y, ab));
        gv.z = se * xx.z * sigmoidf_(fmaf(se, yy.z, ab));
        gv.w = se * xx.w * sigmoidf_(fmaf(se, yy.w, ab));
      }
      *(float4*)&g[GOFF + s * BSZ2 + rb * RSTR + sh0] = gv;  // b128, aligned
    }
    __syncthreads();

    float* dst = (TBL && rep < reps - 1) ? scratch + ((size_t)bc << 12) : yp;

    // Phase 2: gather + max.
    for (int k = 0; k < 16; k++) {
      int wh = (k << 8) | threadIdx.x;
      float m;
      if (TBL) {
        uint4 p = t32[wh];                 // 16B coalesced: taps 0..7
        int p8  = t16[wh];
        float m0 = fmaxf(g[p.x & 0xffffu], g[p.x >> 16]);
        float m1 = fmaxf(g[p.y & 0xffffu], g[p.y >> 16]);
        float m2 = fmaxf(g[p.z & 0xffffu], g[p.z >> 16]);
        float m3 = fmaxf(g[p.w & 0xffffu], g[p.w >> 16]);
        m = fmaxf(fmaxf(fmaxf(m0, m1), fmaxf(m2, m3)), g[p8]);
      } else {
        m = 0.0f;
#pragma unroll
        for (int s = 0; s < 9; s++) m = fmaxf(m, g[tap_off(s, wh)]);
      }
      dst[wh] = m;
    }
    __syncthreads();   // g reuse guard for next rep
  }
}

extern "C" void kernel_launch(void* const* d_in, const int* in_sizes, int n_in,
                              void* d_out, int out_size, void* d_ws, size_t ws_size,
                              hipStream_t stream) {
  const float* x        = (const float*)d_in[0];
  const float* se_param = (const float*)d_in[1];
  const float* attn_w   = (const float*)d_in[2];
  const float* attn_b   = (const float*)d_in[3];
  float* out = (float*)d_out;

  int B = in_sizes[0] / (CCH * SP);
  unsigned* t32       = (unsigned*)d_ws;
  unsigned short* t16 = (unsigned short*)((char*)d_ws + T16_OFF);
  float* scratch      = (float*)((char*)d_ws + SCR_OFFB);
  size_t need = (size_t)SCR_OFFB + (size_t)B * CCH * SP * sizeof(float);
  bool use_ws = ws_size >= need;

  if (use_ws) {
    k_conv<true><<<dim3(TBLK + B * 128), dim3(256), 0, stream>>>(
        x, attn_w, out, t32, t16);
    k_attnmax<true><<<dim3(B * CCH), dim3(256), 0, stream>>>(
        x, out, se_param, attn_b, (const uint4*)t32, t16, scratch);
  } else {
    k_conv<false><<<dim3(B * 128), dim3(256), 0, stream>>>(
        x, attn_w, out, nullptr, nullptr);
    k_attnmax<false><<<dim3(B * CCH), dim3(256), 0, stream>>>(
        x, out, se_param, attn_b, nullptr, nullptr, nullptr);
  }
}

// Round 16
// 30.538 us; speedup vs baseline: 2.0489x; 2.0489x over previous
//
#include <hip/hip_runtime.h>

#define CCH 128
#define SP  4096          // 64*64 spatial positions per (b,c)
#define BROWS 10          // band rows rb in [0,10)
#define RSTR 76           // g rb-stride (floats): rows at bank offsets {0,12,24}
                          // -> 3x10-col windows tile 30/32 banks, conflict-free
#define BSZ2 (BROWS * RSTR)  // 760 floats per band
#define GOFF 16           // g data starts at 16 (64B-aligned); g[0] = sentinel 0
#define GTOT (GOFF + 9 * BSZ2)   // 6856 floats = 27.4 KB
#define T16_OFF 65536     // byte offset of the u16 (s=8) table in d_ws
#define TBLK 80           // table-generator blocks fused into conv grid
#define XTSTR 136         // LDS x_t halfword stride (272B rows)
#define LOG2E 1.4426950408889634f

typedef __attribute__((ext_vector_type(8))) short bf16x8;   // 8 bf16 = 4 VGPRs
typedef __attribute__((ext_vector_type(4))) float f32x4;

__device__ __forceinline__ float sigmoidf_(float z) {
  return 1.0f / (1.0f + __expf(-z));
}

__device__ __forceinline__ unsigned short bf16rne(float f) {
  union { float f; unsigned u; } v; v.f = f;
  return (unsigned short)((v.u + 0x7fffu + ((v.u >> 16) & 1u)) >> 16);
}

// Band-local gather offset for tap s at output wh (g layout [s][rb][sh]):
// GOFF + s*760 + rb*76 + sh, or 0 (sentinel g[0]=0) when source is OOB.
__device__ __forceinline__ int tap_off(int s, int wh) {
  int q  = (s << 12) + wh;     // flat index into torch's reinterpreted view
  int wi = q / 576;  int r  = q - wi * 576;
  int hi = r / 9;    int kk = r - hi * 9;
  int di = kk / 3,   dj = kk - di * 3;
  int sw = wi + di - 1, sh = hi + dj - 1;
  bool valid = ((unsigned)sw < 64u) & ((unsigned)sh < 64u);
  int wilo = (s * 64) / 9;     // first source row of band s
  int rb = sw - wilo + 1;      // in [0,10) for valid sw
  return valid ? (GOFF + s * BSZ2 + rb * RSTR + sh) : 0;
}

// Fused: blocks [0,TBLK) generate gather tables; blocks [TBLK,..) do the conv.
// Conv: y[b,o,n] = sum_c w[o][c]*x[b,c,n] via mfma_f32_16x16x32_bf16.
// Block = 128o x 32n, 4 waves; wave = 32o x 32n = 2 o-tiles x 2 n-tiles.
// A-frags converted in-kernel from fp32 attn_w; A/B share k-slot indexing ->
// invariant to HW k-permutation. C/D (m89): col=lane&15 (n), row=(lane>>4)*4+reg.
template <bool WS>
__global__ __launch_bounds__(256) void k_conv(
    const float* __restrict__ x, const float* __restrict__ attn_w,
    float* __restrict__ y, unsigned* __restrict__ t32,
    unsigned short* __restrict__ t16) {
  int bid = blockIdx.x;
  if (WS) {
    if (bid < TBLK) {   // table generation: 20480 entries, one per thread
      int i = bid * 256 + threadIdx.x;
      if (i < 4 * SP) {
        int wh = i >> 2, j = i & 3;         // t32[wh*4+j] -> taps 2j, 2j+1
        unsigned lo = (unsigned)tap_off(2 * j, wh);
        unsigned hi = (unsigned)tap_off(2 * j + 1, wh);
        t32[i] = lo | (hi << 16);
      } else if (i < 5 * SP) {
        int wh = i & (SP - 1);
        t16[wh] = (unsigned short)tap_off(8, wh);
      }
      return;
    }
    bid -= TBLK;
  }

  __shared__ unsigned short x_t[32 * XTSTR];   // 8704 B

  int b  = bid >> 7;
  int nb = bid & 127;                          // 32n slab
  int lane = threadIdx.x & 63, wv = threadIdx.x >> 6;

  // Issue staging loads first (16 scalar dwords; lanes 0-31 = 128B segments).
  const float* xpb = x + ((size_t)b << 19) + (nb << 5);
  int n_st  = threadIdx.x & 31;
  int c_st  = (threadIdx.x >> 5) << 2;
  float xv[16];
#pragma unroll
  for (int g = 0; g < 4; g++) {
    int c0 = c_st + (g << 5);
#pragma unroll
    for (int i = 0; i < 4; i++)
      xv[g * 4 + i] = xpb[((size_t)(c0 + i) << 12) + n_st];
  }

  // A-fragments from fp32 w (L2-hot 64KB): lane l holds
  // A[o = ot*16 + (l&15)][k = ks*32 + (l>>4)*8 .. +7], converted to bf16.
  bf16x8 afrag[2][4];
#pragma unroll
  for (int ot = 0; ot < 2; ot++)
#pragma unroll
    for (int ks = 0; ks < 4; ks++) {
      int o = (wv << 5) + (ot << 4) + (lane & 15);
      int k = (ks << 5) + ((lane >> 4) << 3);
      const float4* wp = (const float4*)&attn_w[(o << 7) + k];
      float4 a0 = wp[0], a1 = wp[1];
      bf16x8 f;
      f[0] = (short)bf16rne(a0.x); f[1] = (short)bf16rne(a0.y);
      f[2] = (short)bf16rne(a0.z); f[3] = (short)bf16rne(a0.w);
      f[4] = (short)bf16rne(a1.x); f[5] = (short)bf16rne(a1.y);
      f[6] = (short)bf16rne(a1.z); f[7] = (short)bf16rne(a1.w);
      afrag[ot][ks] = f;
    }

  // Convert + write staged x into transposed bf16 LDS x_t[n][k].
#pragma unroll
  for (int g = 0; g < 4; g++) {
    int c0 = c_st + (g << 5);
    union { unsigned short s[2]; unsigned u; } p0, p1;
    p0.s[0] = bf16rne(xv[g * 4 + 0]); p0.s[1] = bf16rne(xv[g * 4 + 1]);
    p1.s[0] = bf16rne(xv[g * 4 + 2]); p1.s[1] = bf16rne(xv[g * 4 + 3]);
    *(uint2*)&x_t[n_st * XTSTR + c0] = make_uint2(p0.u, p1.u);
  }
  __syncthreads();

  f32x4 acc[2][2] = {};
#pragma unroll
  for (int ks = 0; ks < 4; ks++) {
    bf16x8 bfrag[2];
#pragma unroll
    for (int nt = 0; nt < 2; nt++) {
      int n = (nt << 4) + (lane & 15);
      int k = (ks << 5) + ((lane >> 4) << 3);
      bfrag[nt] = *(const bf16x8*)&x_t[n * XTSTR + k];   // ds_read_b128
    }
#pragma unroll
    for (int ot = 0; ot < 2; ot++)
#pragma unroll
      for (int nt = 0; nt < 2; nt++)
        acc[ot][nt] = __builtin_amdgcn_mfma_f32_16x16x32_bf16(
            afrag[ot][ks], bfrag[nt], acc[ot][nt], 0, 0, 0);
  }

  // Epilogue: acc[ot][nt][r] -> y[o][n], o = base + (lane>>4)*4 + r.
  float* yb = y + ((size_t)b << 19) + (nb << 5);
#pragma unroll
  for (int ot = 0; ot < 2; ot++) {
    int ob = (wv << 5) + (ot << 4) + ((lane >> 4) << 2);
#pragma unroll
    for (int nt = 0; nt < 2; nt++) {
      int n = (nt << 4) + (lane & 15);
#pragma unroll
      for (int r = 0; r < 4; r++)
        yb[((size_t)(ob + r) << 12) + n] = acc[ot][nt][r];
    }
  }
}

// out[b,c,wh] = max_s G_s[src(s,wh)], G_s[p] = se[s]*x[p]*sigmoid(se[s]*y[p]+ab).
// Phase 1: G bands, float4 loads + one ds_write_b128 per 4 values; sigmoid via
// exp2 with folded constants. Phase 2: 1 uint4 + 1 u16 table load + 9
// ds_read_b32 (bank-disjoint rows via RSTR=76) + 9 fmax; OOB -> g[0]=0.
template <bool TBL>
__global__ __launch_bounds__(256) void k_attnmax(
    const float* __restrict__ x, float* __restrict__ yo,
    const float* __restrict__ se_param, const float* __restrict__ attn_b,
    const uint4* __restrict__ t32, const unsigned short* __restrict__ t16) {
  __shared__ float g[GTOT];
  __shared__ float se9[16];     // sigmoid(se_param[s])
  __shared__ float sl9[16];     // -se9[s] * log2(e)

  int bc = blockIdx.x;            // b*128 + c
  int c  = bc & (CCH - 1);
  const float* xp = x  + ((size_t)bc << 12);
  float*       yp = yo + ((size_t)bc << 12);

  if (threadIdx.x < 9) {
    float se = sigmoidf_(se_param[threadIdx.x]);
    se9[threadIdx.x] = se;
    sl9[threadIdx.x] = -se * LOG2E;
  }
  if (threadIdx.x == 0) g[0] = 0.0f;
  float ab = attn_b[c];
  float abl = -ab * LOG2E;
  __syncthreads();

  // Phase 1: 1440 float4 units -> (s, rb, sh0). Source row rg = wilo(s)-1+rb.
  for (int f = threadIdx.x; f < 9 * BROWS * 16; f += 256) {
    int s   = f / 160;
    int rem = f - s * 160;
    int rb  = rem >> 4, sh0 = (rem & 15) << 2;
    int rg  = ((s * 64 * 58255) >> 19) - 1 + rb;   // wilo(s) = (s*64)/9
    float4 gv = make_float4(0.0f, 0.0f, 0.0f, 0.0f);
    if ((unsigned)rg < 64u) {
      float se = se9[s], sl = sl9[s];
      float4 xx = *(const float4*)&xp[(rg << 6) + sh0];   // 1KB/wave coalesced
      float4 yy = *(const float4*)&yp[(rg << 6) + sh0];
      // se*x*sigmoid(se*y+ab) = se*x / (1 + exp2(fma(y, -se*log2e, -ab*log2e)))
      gv.x = se * xx.x * __builtin_amdgcn_rcpf(1.0f + exp2f(fmaf(yy.x, sl, abl)));
      gv.y = se * xx.y * __builtin_amdgcn_rcpf(1.0f + exp2f(fmaf(yy.y, sl, abl)));
      gv.z = se * xx.z * __builtin_amdgcn_rcpf(1.0f + exp2f(fmaf(yy.z, sl, abl)));
      gv.w = se * xx.w * __builtin_amdgcn_rcpf(1.0f + exp2f(fmaf(yy.w, sl, abl)));
    }
    *(float4*)&g[GOFF + s * BSZ2 + rb * RSTR + sh0] = gv;  // b128, 16B-aligned
  }
  __syncthreads();

  // Phase 2: gather + max; overwrite the y-plane with the result.
  for (int k = 0; k < 16; k++) {
    int wh = (k << 8) | threadIdx.x;
    float m;
    if (TBL) {
      uint4 p = t32[wh];                 // 16B coalesced: taps 0..7
      int p8  = t16[wh];
      float m0 = fmaxf(g[p.x & 0xffffu], g[p.x >> 16]);
      float m1 = fmaxf(g[p.y & 0xffffu], g[p.y >> 16]);
      float m2 = fmaxf(g[p.z & 0xffffu], g[p.z >> 16]);
      float m3 = fmaxf(g[p.w & 0xffffu], g[p.w >> 16]);
      m = fmaxf(fmaxf(fmaxf(m0, m1), fmaxf(m2, m3)), g[p8]);
    } else {
      m = 0.0f;
#pragma unroll
      for (int s = 0; s < 9; s++) m = fmaxf(m, g[tap_off(s, wh)]);
    }
    yp[wh] = m;
  }
}

extern "C" void kernel_launch(void* const* d_in, const int* in_sizes, int n_in,
                              void* d_out, int out_size, void* d_ws, size_t ws_size,
                              hipStream_t stream) {
  const float* x        = (const float*)d_in[0];
  const float* se_param = (const float*)d_in[1];
  const float* attn_w   = (const float*)d_in[2];
  const float* attn_b   = (const float*)d_in[3];
  float* out = (float*)d_out;

  int B = in_sizes[0] / (CCH * SP);
  unsigned* t32       = (unsigned*)d_ws;
  unsigned short* t16 = (unsigned short*)((char*)d_ws + T16_OFF);
  bool use_ws = ws_size >= (size_t)(T16_OFF + SP * sizeof(unsigned short));

  if (use_ws) {
    k_conv<true><<<dim3(TBLK + B * 128), dim3(256), 0, stream>>>(
        x, attn_w, out, t32, t16);
    k_attnmax<true><<<dim3(B * CCH), dim3(256), 0, stream>>>(
        x, out, se_param, attn_b, (const uint4*)t32, t16);
  } else {
    k_conv<false><<<dim3(B * 128), dim3(256), 0, stream>>>(
        x, attn_w, out, nullptr, nullptr);
    k_attnmax<false><<<dim3(B * CCH), dim3(256), 0, stream>>>(
        x, out, se_param, attn_b, nullptr, nullptr);
  }
}